// Round 3
// baseline (101.369 us; speedup 1.0000x reference)
//
#include <hip/hip_runtime.h>

#define CONF_THRES 0.25f

__device__ __forceinline__ float row_val(const float* __restrict__ post,
                                         const float* __restrict__ boxes, int i) {
    // post row i: cols 4,5 -> float2 at element 6i+4 (8B aligned)
    float2 cs = *reinterpret_cast<const float2*>(post + 6ll * i + 4);
    // boxes row i: float4, 16B aligned
    float4 b = *reinterpret_cast<const float4*>(boxes + 4ll * i);
    float per = cs.y + (b.x + b.y) + (b.z + b.w);
    return (cs.x >= CONF_THRES) ? per : 0.0f;
}

// Fused: 7 unconditional interleaved rows/thread (guaranteed in-bounds when
// 7*T <= n) + 1 predicated row -> 16 loads in flight, no rolled tail.
// Final reduction by the last-finishing block (fence + counter), fixed
// summation order -> deterministic.
__global__ void __launch_bounds__(256) yolo_fused(const float* __restrict__ post,
                                                  const float* __restrict__ boxes,
                                                  float* __restrict__ partials,
                                                  unsigned int* __restrict__ counter,
                                                  float* __restrict__ out, int n) {
    const int T = gridDim.x * blockDim.x;
    const int tid = blockIdx.x * blockDim.x + threadIdx.x;

    float acc = 0.0f;
    long i = tid;
    if (7ll * T <= (long)n) {
        #pragma unroll
        for (int k = 0; k < 7; ++k) {          // all in-bounds by construction
            acc += row_val(post, boxes, (int)i);
            i += T;
        }
        for (; i < n; i += T)                   // at most 1 iteration
            acc += row_val(post, boxes, (int)i);
    } else {                                    // generic fallback
        for (; i < n; i += T)
            acc += row_val(post, boxes, (int)i);
    }

    // wave64 butterfly
    #pragma unroll
    for (int off = 32; off > 0; off >>= 1)
        acc += __shfl_down(acc, off, 64);

    __shared__ float ws[4];
    __shared__ bool is_last;
    int wid = threadIdx.x >> 6;
    if ((threadIdx.x & 63) == 0) ws[wid] = acc;
    __syncthreads();

    if (threadIdx.x == 0) {
        partials[blockIdx.x] = (ws[0] + ws[1]) + (ws[2] + ws[3]);
        __threadfence();                        // publish partial (device scope)
        unsigned old = atomicAdd(counter, 1u);
        is_last = (old == gridDim.x - 1);
    }
    __syncthreads();

    if (is_last) {
        // fixed index order -> deterministic result regardless of which block runs this
        float a2 = 0.0f;
        for (int j = threadIdx.x; j < (int)gridDim.x; j += blockDim.x)
            a2 += __hip_atomic_load(&partials[j], __ATOMIC_RELAXED,
                                    __HIP_MEMORY_SCOPE_AGENT);
        #pragma unroll
        for (int off = 32; off > 0; off >>= 1)
            a2 += __shfl_down(a2, off, 64);
        if ((threadIdx.x & 63) == 0) ws[wid] = a2;
        __syncthreads();
        if (threadIdx.x == 0)
            out[0] = (ws[0] + ws[1]) + (ws[2] + ws[3]);
    }
}

extern "C" void kernel_launch(void* const* d_in, const int* in_sizes, int n_in,
                              void* d_out, int out_size, void* d_ws, size_t ws_size,
                              hipStream_t stream) {
    const float* post  = (const float*)d_in[0];   // [N,6] f32
    const float* boxes = (const float*)d_in[1];   // [N,4] f32
    float* out = (float*)d_out;                   // scalar f32

    unsigned int* counter = (unsigned int*)d_ws;          // 4 B
    float* partials = (float*)((char*)d_ws + 256);        // 2048 floats

    int n = in_sizes[0] / 6;                      // N = 4,000,000

    const int block = 256;
    int blocks = 2048;                            // T = 524288; 7T = 3.67M <= N
    int needed = (n + block - 1) / block;
    if (blocks > needed) blocks = needed;

    // counter must be 0 at every call (graph-replay safe async memset)
    hipMemsetAsync(counter, 0, sizeof(unsigned int), stream);

    yolo_fused<<<blocks, block, 0, stream>>>(post, boxes, partials, counter, out, n);
}

// Round 4
// 33.395 us; speedup vs baseline: 3.0355x; 3.0355x over previous
//
#include <hip/hip_runtime.h>

#define CONF_THRES 0.25f

__device__ __forceinline__ float row_val(const float* __restrict__ post,
                                         const float* __restrict__ boxes, int i) {
    // post row i: cols 4,5 -> float2 at element 6i+4 (8B aligned)
    float2 cs = *reinterpret_cast<const float2*>(post + 6ll * i + 4);
    // boxes row i: float4, 16B aligned
    float4 b = *reinterpret_cast<const float4*>(boxes + 4ll * i);
    float per = cs.y + (b.x + b.y) + (b.z + b.w);
    return (cs.x >= CONF_THRES) ? per : 0.0f;
}

// Stage 1: exactly 8 strided rows per thread. Rows 0..6 provably in-bounds
// (tid + 6T < 7T <= N); only row 7 predicated. Two 4-row batches -> 8 loads
// in flight over 100% of the work, no rolled tail. One plain store per block.
__global__ void __launch_bounds__(256) yolo_partial(const float* __restrict__ post,
                                                    const float* __restrict__ boxes,
                                                    float* __restrict__ partials, int n) {
    const int T = gridDim.x * blockDim.x;
    const int tid = blockIdx.x * blockDim.x + threadIdx.x;

    float acc;
    if (7 * (long long)T <= n) {                 // fast path (always taken here)
        float a0 = row_val(post, boxes, tid);
        float a1 = row_val(post, boxes, tid + T);
        float a2 = row_val(post, boxes, tid + 2 * T);
        float a3 = row_val(post, boxes, tid + 3 * T);
        float s0 = (a0 + a1) + (a2 + a3);

        float a4 = row_val(post, boxes, tid + 4 * T);
        float a5 = row_val(post, boxes, tid + 5 * T);
        float a6 = row_val(post, boxes, tid + 6 * T);
        int i7 = tid + 7 * T;
        float a7 = (i7 < n) ? row_val(post, boxes, i7) : 0.0f;
        float s1 = (a4 + a5) + (a6 + a7);
        acc = s0 + s1;
    } else {                                     // generic fallback
        acc = 0.0f;
        for (int i = tid; i < n; i += T)
            acc += row_val(post, boxes, i);
    }

    // wave64 butterfly
    #pragma unroll
    for (int off = 32; off > 0; off >>= 1)
        acc += __shfl_down(acc, off, 64);

    __shared__ float ws[4];
    int wid = threadIdx.x >> 6;
    if ((threadIdx.x & 63) == 0) ws[wid] = acc;
    __syncthreads();
    if (threadIdx.x == 0)
        partials[blockIdx.x] = (ws[0] + ws[1]) + (ws[2] + ws[3]);
}

// Stage 2: one block sums the per-block partials and writes the scalar.
__global__ void __launch_bounds__(256) yolo_final(const float* __restrict__ partials,
                                                  float* __restrict__ out, int m) {
    float acc = 0.0f;
    for (int i = threadIdx.x; i < m; i += blockDim.x)
        acc += partials[i];

    #pragma unroll
    for (int off = 32; off > 0; off >>= 1)
        acc += __shfl_down(acc, off, 64);

    __shared__ float ws[4];
    int wid = threadIdx.x >> 6;
    if ((threadIdx.x & 63) == 0) ws[wid] = acc;
    __syncthreads();
    if (threadIdx.x == 0)
        out[0] = (ws[0] + ws[1]) + (ws[2] + ws[3]);
}

extern "C" void kernel_launch(void* const* d_in, const int* in_sizes, int n_in,
                              void* d_out, int out_size, void* d_ws, size_t ws_size,
                              hipStream_t stream) {
    const float* post  = (const float*)d_in[0];   // [N,6] f32
    const float* boxes = (const float*)d_in[1];   // [N,4] f32
    float* out = (float*)d_out;                   // scalar f32
    float* partials = (float*)d_ws;               // 2048 floats of scratch

    int n = in_sizes[0] / 6;                      // N = 4,000,000

    const int block = 256;
    int blocks = 2048;                            // T = 524288; 7T = 3.67M <= N
    int needed = (n + block - 1) / block;
    if (blocks > needed) blocks = needed;

    yolo_partial<<<blocks, block, 0, stream>>>(post, boxes, partials, n);
    yolo_final<<<1, block, 0, stream>>>(partials, out, blocks);
}

// Round 5
// 30.394 us; speedup vs baseline: 3.3351x; 1.0987x over previous
//
#include <hip/hip_runtime.h>

#define CONF_THRES 0.25f

__device__ __forceinline__ float row_val(const float* __restrict__ post,
                                         const float* __restrict__ boxes, int i) {
    // post row i: cols 4,5 -> float2 at element 6i+4 (8B aligned)
    float2 cs = *reinterpret_cast<const float2*>(post + 6ll * i + 4);
    // boxes row i: float4, 16B aligned
    float4 b = *reinterpret_cast<const float4*>(boxes + 4ll * i);
    float per = cs.y + (b.x + b.y) + (b.z + b.w);
    return (cs.x >= CONF_THRES) ? per : 0.0f;
}

// Stage 1: 8 strided rows/thread (rows 0..6 provably in-bounds when 7T <= n,
// row 7 predicated). block=1024 -> only 512 blocks, fewer epilogues/partials.
__global__ void __launch_bounds__(1024) yolo_partial(const float* __restrict__ post,
                                                     const float* __restrict__ boxes,
                                                     float* __restrict__ partials, int n) {
    const int T = gridDim.x * blockDim.x;
    const int tid = blockIdx.x * blockDim.x + threadIdx.x;

    float acc;
    if (7 * (long long)T <= n) {                 // fast path (always taken here)
        float a0 = row_val(post, boxes, tid);
        float a1 = row_val(post, boxes, tid + T);
        float a2 = row_val(post, boxes, tid + 2 * T);
        float a3 = row_val(post, boxes, tid + 3 * T);
        float s0 = (a0 + a1) + (a2 + a3);

        float a4 = row_val(post, boxes, tid + 4 * T);
        float a5 = row_val(post, boxes, tid + 5 * T);
        float a6 = row_val(post, boxes, tid + 6 * T);
        int i7 = tid + 7 * T;
        float a7 = (i7 < n) ? row_val(post, boxes, i7) : 0.0f;
        float s1 = (a4 + a5) + (a6 + a7);
        acc = s0 + s1;
    } else {                                     // generic fallback
        acc = 0.0f;
        for (int i = tid; i < n; i += T)
            acc += row_val(post, boxes, i);
    }

    // wave64 butterfly
    #pragma unroll
    for (int off = 32; off > 0; off >>= 1)
        acc += __shfl_down(acc, off, 64);

    __shared__ float ws[16];
    int wid = threadIdx.x >> 6;
    if ((threadIdx.x & 63) == 0) ws[wid] = acc;
    __syncthreads();

    if (threadIdx.x < 64) {
        // 16 wave-partials reduced by the first wave
        float v = (threadIdx.x < 16) ? ws[threadIdx.x] : 0.0f;
        #pragma unroll
        for (int off = 8; off > 0; off >>= 1)
            v += __shfl_down(v, off, 64);
        if (threadIdx.x == 0) partials[blockIdx.x] = v;
    }
}

// Stage 2: ONE wave. 512 partials = 128 float4 = 2 float4/lane. No LDS.
__global__ void __launch_bounds__(64) yolo_final(const float4* __restrict__ partials4,
                                                 float* __restrict__ out) {
    float4 p0 = partials4[threadIdx.x];           // lanes 0..63 -> float4 0..63
    float4 p1 = partials4[threadIdx.x + 64];      // float4 64..127
    float acc = ((p0.x + p0.y) + (p0.z + p0.w)) + ((p1.x + p1.y) + (p1.z + p1.w));

    #pragma unroll
    for (int off = 32; off > 0; off >>= 1)
        acc += __shfl_down(acc, off, 64);

    if (threadIdx.x == 0) out[0] = acc;
}

extern "C" void kernel_launch(void* const* d_in, const int* in_sizes, int n_in,
                              void* d_out, int out_size, void* d_ws, size_t ws_size,
                              hipStream_t stream) {
    const float* post  = (const float*)d_in[0];   // [N,6] f32
    const float* boxes = (const float*)d_in[1];   // [N,4] f32
    float* out = (float*)d_out;                   // scalar f32
    float* partials = (float*)d_ws;               // 512 floats (16B-aligned ws)

    int n = in_sizes[0] / 6;                      // N = 4,000,000

    const int block = 1024;
    const int blocks = 512;                       // T = 524288; 7T = 3.67M <= N

    yolo_partial<<<blocks, block, 0, stream>>>(post, boxes, partials, n);
    yolo_final<<<1, 64, 0, stream>>>((const float4*)partials, out);
}